// Round 1
// baseline (339.199 us; speedup 1.0000x reference)
//
#include <hip/hip_runtime.h>
#include <stdint.h>

#define HW 3136      // 56*56
#define K_SEL 313    // int(0.1*3136)
#define NTH 256
#define NV4 784      // 3136/4
#define NROWS 16384  // 64*256
#define CAND_CAP 1024
#define FAST_CAP 512

// Fast-path band: threshold = upper-0.0998 quantile of a 3136-sample N(0,1)
// row = 1.283 +/- 0.031 (1 sigma). [0.8, 1.8) is +/-16 sigma -> essentially
// always brackets it. Exact slow-path fallback handles everything else.
#define BAND_LO  0.8f
#define BAND_HI  1.8f
#define BAND_INV 128.0f   // 128 bins over [0.8, 1.8), width 1/128

__device__ __forceinline__ uint32_t f2k(float f) {
    uint32_t u = __float_as_uint(f);
    return (u & 0x80000000u) ? ~u : (u | 0x80000000u);
}
// slow-path 256-bin map over [-4,4): clamp((int)((x+4)*32), 0, 255)
__device__ __forceinline__ int binOf(float x) {
    int b = (int)((x + 4.0f) * 32.0f);
    return min(255, max(0, b));
}
// fast-path: bin for x >= BAND_LO. 0..127 inside band, 128 = overflow (>= HI).
// Monotone: x>=LO gives (x-LO)>=0 exactly; trunc==floor; min() keeps order.
__device__ __forceinline__ int bandBin(float x) {
    return (x >= BAND_HI) ? 128 : min(127, (int)((x - BAND_LO) * BAND_INV));
}

__global__ __launch_bounds__(NTH) void wta2d_kernel(const float* __restrict__ x,
                                                    float* __restrict__ out) {
    __shared__ int hist[4][256];        // per-wave private histograms
    __shared__ uint32_t cand[CAND_CAP];
    __shared__ int wsum[4];
    __shared__ int sh_m;
    __shared__ int sh_bin, sh_k2;
    __shared__ uint32_t sh_tkey;

    const int tid  = threadIdx.x;
    const int wave = tid >> 6;
    const int lane = tid & 63;
    const int row  = blockIdx.x;
    const float4* xrow = (const float4*)(x + (size_t)row * HW);
    float4*       orow = (float4*)(out + (size_t)row * HW);

    // ---- A: zero hist (bins 0..255 cover both paths' needs) ----
    #pragma unroll
    for (int w = 0; w < 4; w++) hist[w][tid] = 0;
    if (tid == 0) { sh_m = 0; sh_bin = -1; }
    __syncthreads();

    // ---- B: load row into REGISTERS; histogram ONLY the band tail ----
    float4 r[4];
    const int nv = (tid < (NV4 - 3 * NTH)) ? 4 : 3;   // first 16 threads take 4
    #pragma unroll
    for (int j = 0; j < 4; j++) {
        if (j < nv) {
            float4 v = xrow[tid + j * NTH];
            r[j] = v;
            float a[4] = {v.x, v.y, v.z, v.w};
            #pragma unroll
            for (int q = 0; q < 4; q++) {
                float xv = a[q];
                if (xv >= BAND_LO) {                 // ~21% of elements
                    atomicAdd(&hist[wave][bandBin(xv)], 1);
                }
            }
        }
    }
    __syncthreads();

    // ---- C: suffix scan over the 128 band bins (2 waves); c_hi from bin 128 ----
    int g = 0, s = 0;
    if (tid < 128) {
        const int t = 127 - tid;                    // wave0: t=127..64, wave1: t=63..0
        g = hist[0][t] + hist[1][t] + hist[2][t] + hist[3][t];
        s = g;
        #pragma unroll
        for (int off = 1; off < 64; off <<= 1) {
            int n = __shfl_up(s, off, 64);
            if (lane >= off) s += n;
        }
        if (lane == 63) wsum[wave] = s;
    }
    __syncthreads();
    if (tid < 128) {
        if (wave == 1) s += wsum[0];
        const int c_hi = hist[0][128] + hist[1][128] + hist[2][128] + hist[3][128];
        const int above = c_hi + s;                 // #elements >= lower edge of bin t
        if (above >= K_SEL && (above - g) < K_SEL) {
            sh_bin = 127 - tid;
            sh_k2  = K_SEL - (above - g);           // residual rank inside the bin
        }
        // threshold >= BAND_HI  -> c_hi >= K   -> no bin matches -> sh_bin stays -1
        // threshold <  BAND_LO  -> above < K at t=0              -> sh_bin stays -1
    }
    __syncthreads();

    bool fast = (sh_bin >= 0);                      // block-uniform
    if (fast) {
        const int tbin = sh_bin;
        const int k2   = sh_k2;
        // ---- compact the target bin's candidates straight from registers ----
        #pragma unroll
        for (int j = 0; j < 4; j++) {
            if (j < nv) {
                float a[4] = {r[j].x, r[j].y, r[j].z, r[j].w};
                #pragma unroll
                for (int q = 0; q < 4; q++) {
                    float xv = a[q];
                    if (xv >= BAND_LO && bandBin(xv) == tbin) {
                        int idx = atomicAdd(&sh_m, 1);
                        if (idx < FAST_CAP) cand[idx] = f2k(xv);
                    }
                }
            }
        }
        __syncthreads();
        const int m = sh_m;                         // ~5 expected
        if (m > FAST_CAP) {
            fast = false;                           // uniform; exact fallback below
        } else {
            for (int j = tid; j < m; j += NTH) {
                uint32_t kj = cand[j];
                int gt = 0, ge = 0;
                for (int i = 0; i < m; i++) {
                    uint32_t ki = cand[i];
                    gt += (ki > kj) ? 1 : 0;
                    ge += (ki >= kj) ? 1 : 0;
                }
                if (gt < k2 && ge >= k2) sh_tkey = kj;
            }
            __syncthreads();
        }
    }

    if (!fast) {
        // ======== exact fallback: full 256-bin histogram over [-4,4) ========
        #pragma unroll
        for (int w = 0; w < 4; w++) hist[w][tid] = 0;
        if (tid == 0) sh_m = 0;
        __syncthreads();
        #pragma unroll
        for (int j = 0; j < 4; j++) {
            if (j < nv) {
                float a[4] = {r[j].x, r[j].y, r[j].z, r[j].w};
                #pragma unroll
                for (int q = 0; q < 4; q++) atomicAdd(&hist[wave][binOf(a[q])], 1);
            }
        }
        __syncthreads();
        const int t = 255 - tid;
        int g2 = hist[0][t] + hist[1][t] + hist[2][t] + hist[3][t];
        int s2 = g2;
        #pragma unroll
        for (int off = 1; off < 64; off <<= 1) {
            int n = __shfl_up(s2, off, 64);
            if (lane >= off) s2 += n;
        }
        if (lane == 63) wsum[wave] = s2;
        __syncthreads();
        #pragma unroll
        for (int w = 0; w < 3; w++) if (w < wave) s2 += wsum[w];
        if (s2 >= K_SEL && (s2 - g2) < K_SEL) {
            sh_bin = t;
            sh_k2  = K_SEL - (s2 - g2);
        }
        __syncthreads();
        const int tbin = sh_bin;
        const int k2   = sh_k2;
        #pragma unroll
        for (int j = 0; j < 4; j++) {
            if (j < nv) {
                float a[4] = {r[j].x, r[j].y, r[j].z, r[j].w};
                #pragma unroll
                for (int q = 0; q < 4; q++) {
                    if (binOf(a[q]) == tbin) {
                        int idx = atomicAdd(&sh_m, 1);
                        if (idx < CAND_CAP) cand[idx] = f2k(a[q]);
                    }
                }
            }
        }
        __syncthreads();
        const int m = min(sh_m, CAND_CAP);
        for (int j = tid; j < m; j += NTH) {
            uint32_t kj = cand[j];
            int gt = 0, ge = 0;
            for (int i = 0; i < m; i++) {
                uint32_t ki = cand[i];
                gt += (ki > kj) ? 1 : 0;
                ge += (ki >= kj) ? 1 : 0;
            }
            if (gt < k2 && ge >= k2) sh_tkey = kj;
        }
        __syncthreads();
    }

    // ---- output straight from registers ----
    uint32_t tk = sh_tkey;
    uint32_t tb = (tk & 0x80000000u) ? (tk ^ 0x80000000u) : ~tk;
    const float tval = __uint_as_float(tb);
    #pragma unroll
    for (int j = 0; j < 4; j++) {
        if (j < nv) {
            float4 v = r[j];
            float4 o;
            o.x = (v.x < tval) ? v.x : 0.0f;
            o.y = (v.y < tval) ? v.y : 0.0f;
            o.z = (v.z < tval) ? v.z : 0.0f;
            o.w = (v.w < tval) ? v.w : 0.0f;
            orow[tid + j * NTH] = o;
        }
    }
}

extern "C" void kernel_launch(void* const* d_in, const int* in_sizes, int n_in,
                              void* d_out, int out_size, void* d_ws, size_t ws_size,
                              hipStream_t stream) {
    const float* x = (const float*)d_in[0];
    float* out = (float*)d_out;
    wta2d_kernel<<<NROWS, NTH, 0, stream>>>(x, out);
}